// Round 1
// baseline (397.586 us; speedup 1.0000x reference)
//
#include <hip/hip_runtime.h>

// TRF aligner: out[d, t] = sum over seq with s=sourceIdx[seq], 0 <= t-s < N_WIN
// of TRFs[seq, t-s, d]. Gather formulation (no atomics): sourceIdx is sorted,
// so each t-tile binary-searches its contributing seq range.
//
// R3 change vs R2: float4 (d-quad) restructure. Thread tid = (ig<<5)|dq now
// owns d = 4*dq..4*dq+3 and t = t0 + ig*8 .. +7. Loads are global_load_dwordx4
// (1 KB per wave instruction vs 256 B before): 4x fewer load instructions and
// ~4x less clamp/address VALU for identical bytes. Predication is one cndmask
// (m = 0/1) + 4 FMAs per quad. acc/v statically indexed -> stay in VGPRs.

#define T_TILE  32   // t-values per block; 100000 = 3125 * 32 exactly
#define OUT_DIM 128
#define N_WIN   128
#define I_PER   8    // t-values per thread = T_TILE / (128 threads / 32 dq)

__global__ __launch_bounds__(128, 4) void trf_gather_kernel(
    const float* __restrict__ TRFs,      // (nSeq, N_WIN, OUT_DIM)
    const int*   __restrict__ sourceIdx, // (nSeq,) sorted
    int nSeq, int nRealLen,
    float* __restrict__ out)             // (OUT_DIM, nRealLen)
{
    const int tid = threadIdx.x;
    const int dq  = tid & 31;            // d-quad index: d = 4*dq + c
    const int ig  = tid >> 5;            // i-group: i = ig*8 + ii
    const int t0  = blockIdx.x * T_TILE;
    if (t0 >= nRealLen) return;

    // lo = first seq with sourceIdx[seq] >= t0 - (N_WIN-1)
    int lo;
    {
        int target = t0 - (N_WIN - 1);
        int a = 0, b = nSeq;
        while (a < b) { int m = (a + b) >> 1; if (sourceIdx[m] < target) a = m + 1; else b = m; }
        lo = a;
    }
    // hi = first seq with sourceIdx[seq] >= t0 + T_TILE
    int hi;
    {
        int target = t0 + T_TILE;
        int a = lo, b = nSeq;
        while (a < b) { int m = (a + b) >> 1; if (sourceIdx[m] < target) a = m + 1; else b = m; }
        hi = a;
    }

    float acc[I_PER][4];
#pragma unroll
    for (int i = 0; i < I_PER; ++i)
#pragma unroll
        for (int c = 0; c < 4; ++c) acc[i][c] = 0.f;

    const int    ibase = ig * I_PER;     // first i this thread owns
    const float* col   = TRFs + 4 * dq;  // + seq*(N_WIN*OUT_DIM) + k*OUT_DIM

    for (int seq = lo; seq < hi; ++seq) {
        const int s  = sourceIdx[seq];   // wave-uniform -> scalar load
        const int kb = t0 + ibase - s;   // k for ii is kb + ii
        const float* row = col + (size_t)seq * (N_WIN * OUT_DIM);

        // Phase 1: 8 unconditional, independent dwordx4 loads. Clamped k
        // stays inside this seq's row -> always a legal address; clamp
        // duplicates are same-address L1 broadcasts.
        float4 v[I_PER];
#pragma unroll
        for (int ii = 0; ii < I_PER; ++ii) {
            int k  = kb + ii;
            int kc = k < 0 ? 0 : (k > (N_WIN - 1) ? (N_WIN - 1) : k);
            v[ii] = *reinterpret_cast<const float4*>(row + kc * OUT_DIM);
        }
        // Phase 2: predicated accumulate (0/1 multiplier -> cndmask + 4 fma)
#pragma unroll
        for (int ii = 0; ii < I_PER; ++ii) {
            int   k = kb + ii;
            float m = (k >= 0 && k < N_WIN) ? 1.0f : 0.0f;
            acc[ii][0] += v[ii].x * m;
            acc[ii][1] += v[ii].y * m;
            acc[ii][2] += v[ii].z * m;
            acc[ii][3] += v[ii].w * m;
        }
    }

    // Store: thread owns out[4*dq+c, tb : tb+8] for c=0..3 -> 2 float4 each.
    // tb = t0 + ig*8 is a multiple of 8; nRealLen % 4 == 0 keeps 16B alignment.
    const int tb = t0 + ibase;
    if (tb + I_PER <= nRealLen && (nRealLen & 3) == 0) {
#pragma unroll
        for (int c = 0; c < 4; ++c) {
            float* o = out + (size_t)(4 * dq + c) * nRealLen + tb;
            *reinterpret_cast<float4*>(o)     = make_float4(acc[0][c], acc[1][c], acc[2][c], acc[3][c]);
            *reinterpret_cast<float4*>(o + 4) = make_float4(acc[4][c], acc[5][c], acc[6][c], acc[7][c]);
        }
    } else {
#pragma unroll
        for (int c = 0; c < 4; ++c) {
            float* o = out + (size_t)(4 * dq + c) * nRealLen + tb;
            for (int ii = 0; ii < I_PER && tb + ii < nRealLen; ++ii) o[ii] = acc[ii][c];
        }
    }
}

extern "C" void kernel_launch(void* const* d_in, const int* in_sizes, int n_in,
                              void* d_out, int out_size, void* d_ws, size_t ws_size,
                              hipStream_t stream) {
    const float* TRFs      = (const float*)d_in[0];
    const int*   sourceIdx = (const int*)d_in[1];
    const int    nSeq      = in_sizes[1];
    const int    nRealLen  = out_size / OUT_DIM;   // out is OUT_DIM x nRealLen fp32

    const int nBlocks = (nRealLen + T_TILE - 1) / T_TILE;
    trf_gather_kernel<<<nBlocks, 128, 0, stream>>>(
        TRFs, sourceIdx, nSeq, nRealLen, (float*)d_out);
}